// Round 6
// baseline (116.980 us; speedup 1.0000x reference)
//
#include <hip/hip_runtime.h>
#include <hip/hip_bf16.h>

#define H 1024
#define B 64
#define KC 8            // k-chunks in A1
#define KLEN (H / KC)   // 128
#define LT 2            // l's per block in fused kernel

typedef float floatx4 __attribute__((ext_vector_type(4)));

// A1: part[kc][b][h] = sum_{k in chunk kc} hidden[b,k] * W[k,h]
// grid (B/2, KC), block 256. 2 b's per block -> W re-read 32x (L2-resident).
__global__ __launch_bounds__(256) void projA1(
    const float* __restrict__ hidden,   // [B, H]
    const float* __restrict__ W,        // [H, H]
    float* __restrict__ part)           // [KC, B, H]
{
    const int b0 = blockIdx.x * 2;
    const int kc = blockIdx.y;
    const int t  = threadIdx.x;
    const float* h0 = hidden + (size_t)b0 * H + (size_t)kc * KLEN;
    const float* h1 = h0 + H;
    const float4* Wr = (const float4*)(W + (size_t)kc * KLEN * H) + t;

    float4 a0 = {0.f, 0.f, 0.f, 0.f};
    float4 a1 = {0.f, 0.f, 0.f, 0.f};
    #pragma unroll 8
    for (int k = 0; k < KLEN; ++k) {
        const float4 w = Wr[(size_t)k * (H / 4)];
        const float s0 = h0[k];
        const float s1 = h1[k];
        a0.x += s0 * w.x; a0.y += s0 * w.y; a0.z += s0 * w.z; a0.w += s0 * w.w;
        a1.x += s1 * w.x; a1.y += s1 * w.y; a1.z += s1 * w.z; a1.w += s1 * w.w;
    }
    ((float4*)(part + ((size_t)kc * B + b0) * H))[t]     = a0;
    ((float4*)(part + ((size_t)kc * B + b0 + 1) * H))[t] = a1;
}

// A2: u[b,h] = sum_kc part[kc][b][h];  c[b] = hidden[b]·bias. grid (B), block 256.
__global__ __launch_bounds__(256) void projA2(
    const float* __restrict__ part,     // [KC, B, H]
    const float* __restrict__ hidden,   // [B, H]
    const float* __restrict__ bias,     // [H]
    float* __restrict__ u,              // [B, H]
    float* __restrict__ c)              // [B]
{
    const int b = blockIdx.x;
    const int t = threadIdx.x;

    float4 a = {0.f, 0.f, 0.f, 0.f};
    #pragma unroll
    for (int kc = 0; kc < KC; ++kc) {
        const float4 p = ((const float4*)(part + ((size_t)kc * B + b) * H))[t];
        a.x += p.x; a.y += p.y; a.z += p.z; a.w += p.w;
    }
    ((float4*)(u + (size_t)b * H))[t] = a;

    float s = 0.f;
    #pragma unroll
    for (int j = 0; j < H / 256; ++j)
        s += hidden[(size_t)b * H + t + j * 256] * bias[t + j * 256];
    __shared__ float red[256];
    red[t] = s;
    __syncthreads();
    for (int st = 128; st > 0; st >>= 1) {
        if (t < st) red[t] += red[t + st];
        __syncthreads();
    }
    if (t == 0) c[b] = red[0];
}

// Fused B: energies + softmax-over-b + write. grid (L/LT), block 256 (4 waves).
// Wave w handles b in [16w, 16w+16) for LT l's. The 16 b-tasks are independent
// -> deep MLP. u streamed from L2 (256 KiB, cache-resident); enc nontemporal.
__global__ __launch_bounds__(256) void energy_softmax_fused(
    const float* __restrict__ enc,   // [L, B, H]
    const float* __restrict__ u,     // [B, H]
    const float* __restrict__ c,     // [B]
    float* __restrict__ out,         // [B, 1, L] flat
    int L)
{
    const int l0   = blockIdx.x * LT;
    const int wave = threadIdx.x >> 6;
    const int lane = threadIdx.x & 63;

    __shared__ float e_s[LT][B];

    #pragma unroll
    for (int i = 0; i < LT; ++i) {
        const int l = l0 + i;
        const float* encl = enc + (size_t)l * B * H;
        #pragma unroll 4
        for (int j = 0; j < 16; ++j) {
            const int b = wave * 16 + j;
            const floatx4* e4 = (const floatx4*)(encl + (size_t)b * H);
            const float4*  u4 = (const float4*)(u + (size_t)b * H);
            float acc = 0.f;
            #pragma unroll
            for (int q = 0; q < 4; ++q) {
                const floatx4 v  = __builtin_nontemporal_load(e4 + lane + q * 64);
                const float4  uu = u4[lane + q * 64];
                acc += v.x * uu.x + v.y * uu.y + v.z * uu.z + v.w * uu.w;
            }
            #pragma unroll
            for (int off = 32; off > 0; off >>= 1) acc += __shfl_down(acc, off, 64);
            if (lane == 0) e_s[i][b] = acc + c[b];
        }
    }
    __syncthreads();

    // softmax over b: wave i handles l0+i, lane = b
    if (wave < LT) {
        const float e = e_s[wave][lane];
        float m = e;
        #pragma unroll
        for (int off = 32; off > 0; off >>= 1) m = fmaxf(m, __shfl_xor(m, off, 64));
        const float ex = __expf(e - m);
        float s = ex;
        #pragma unroll
        for (int off = 32; off > 0; off >>= 1) s += __shfl_xor(s, off, 64);
        out[(size_t)lane * L + l0 + wave] = ex / s;
    }
}

extern "C" void kernel_launch(void* const* d_in, const int* in_sizes, int n_in,
                              void* d_out, int out_size, void* d_ws, size_t ws_size,
                              hipStream_t stream) {
    const float* hidden = (const float*)d_in[0];  // [1, 64, 1024]
    const float* enc    = (const float*)d_in[1];  // [L, 64, 1024]
    const float* W      = (const float*)d_in[2];  // [1024, 1024]
    const float* bias   = (const float*)d_in[3];  // [1024]
    float* out = (float*)d_out;                   // [64, 1, L]

    const int L = in_sizes[1] / (B * H);          // 2048

    float* part = (float*)d_ws;                   // KC*B*H floats (2 MiB)
    float* u    = part + (size_t)KC * B * H;      // B*H floats
    float* c    = u + (size_t)B * H;              // B floats

    dim3 gridA1(B / 2, KC);
    projA1<<<gridA1, 256, 0, stream>>>(hidden, W, part);

    projA2<<<B, 256, 0, stream>>>(part, hidden, bias, u, c);

    energy_softmax_fused<<<L / LT, 256, 0, stream>>>(enc, u, c, out, L);
}

// Round 7
// 98.067 us; speedup vs baseline: 1.1929x; 1.1929x over previous
//
#include <hip/hip_runtime.h>
#include <hip/hip_bf16.h>

#define H 1024
#define B 64
#define KC 8            // k-chunks in A1
#define KLEN (H / KC)   // 128
#define LT 4            // l's per block in fused kernel

typedef float floatx4 __attribute__((ext_vector_type(4)));

// A1: part[kc][b][h] = sum_{k in chunk kc} hidden[b,k] * W[k,h]
// grid (B/4, KC), block 256. 4 b's per block -> W re-read 16x (64 MiB L2).
__global__ __launch_bounds__(256) void projA1(
    const float* __restrict__ hidden,   // [B, H]
    const float* __restrict__ W,        // [H, H]
    float* __restrict__ part)           // [KC, B, H]
{
    const int b0 = blockIdx.x * 4;
    const int kc = blockIdx.y;
    const int t  = threadIdx.x;
    const float* h0 = hidden + (size_t)(b0 + 0) * H + (size_t)kc * KLEN;
    const float* h1 = h0 + H;
    const float* h2 = h1 + H;
    const float* h3 = h2 + H;
    const float4* Wr = (const float4*)(W + (size_t)kc * KLEN * H) + t;

    float4 a0 = {0.f, 0.f, 0.f, 0.f};
    float4 a1 = {0.f, 0.f, 0.f, 0.f};
    float4 a2 = {0.f, 0.f, 0.f, 0.f};
    float4 a3 = {0.f, 0.f, 0.f, 0.f};
    #pragma unroll 8
    for (int k = 0; k < KLEN; ++k) {
        const float4 w = Wr[(size_t)k * (H / 4)];
        const float s0 = h0[k], s1 = h1[k], s2 = h2[k], s3 = h3[k];
        a0.x += s0 * w.x; a0.y += s0 * w.y; a0.z += s0 * w.z; a0.w += s0 * w.w;
        a1.x += s1 * w.x; a1.y += s1 * w.y; a1.z += s1 * w.z; a1.w += s1 * w.w;
        a2.x += s2 * w.x; a2.y += s2 * w.y; a2.z += s2 * w.z; a2.w += s2 * w.w;
        a3.x += s3 * w.x; a3.y += s3 * w.y; a3.z += s3 * w.z; a3.w += s3 * w.w;
    }
    ((float4*)(part + ((size_t)kc * B + b0 + 0) * H))[t] = a0;
    ((float4*)(part + ((size_t)kc * B + b0 + 1) * H))[t] = a1;
    ((float4*)(part + ((size_t)kc * B + b0 + 2) * H))[t] = a2;
    ((float4*)(part + ((size_t)kc * B + b0 + 3) * H))[t] = a3;
}

// A2: u[b,h] = sum_kc part[kc][b][h];  c[b] = hidden[b]·bias. grid (B), block 256.
__global__ __launch_bounds__(256) void projA2(
    const float* __restrict__ part,     // [KC, B, H]
    const float* __restrict__ hidden,   // [B, H]
    const float* __restrict__ bias,     // [H]
    float* __restrict__ u,              // [B, H]
    float* __restrict__ c)              // [B]
{
    const int b = blockIdx.x;
    const int t = threadIdx.x;

    float4 a = {0.f, 0.f, 0.f, 0.f};
    #pragma unroll
    for (int kc = 0; kc < KC; ++kc) {
        const float4 p = ((const float4*)(part + ((size_t)kc * B + b) * H))[t];
        a.x += p.x; a.y += p.y; a.z += p.z; a.w += p.w;
    }
    ((float4*)(u + (size_t)b * H))[t] = a;

    float s = 0.f;
    #pragma unroll
    for (int j = 0; j < H / 256; ++j)
        s += hidden[(size_t)b * H + t + j * 256] * bias[t + j * 256];
    __shared__ float red[256];
    red[t] = s;
    __syncthreads();
    for (int st = 128; st > 0; st >>= 1) {
        if (t < st) red[t] += red[t + st];
        __syncthreads();
    }
    if (t == 0) c[b] = red[0];
}

// Fused B: energies + softmax-over-b + write. grid (L/LT), block 256 (4 waves).
// Wave w owns b in [16w,16w+16) for LT=4 l's. j (b) OUTER, l INNER: u row
// loaded once into registers per j and reused x4. 16 independent enc loads
// per j -> deep memory-level parallelism. enc nontemporal (one-touch).
__global__ __launch_bounds__(256) void energy_softmax_fused(
    const float* __restrict__ enc,   // [L, B, H]
    const float* __restrict__ u,     // [B, H]
    const float* __restrict__ c,     // [B]
    float* __restrict__ out,         // [B, 1, L] flat
    int L)
{
    const int l0   = blockIdx.x * LT;
    const int wave = threadIdx.x >> 6;
    const int lane = threadIdx.x & 63;

    __shared__ float e_s[LT][B];

    for (int j = 0; j < 16; ++j) {
        const int b = wave * 16 + j;
        const float4* u4 = (const float4*)(u + (size_t)b * H);
        float4 uu[4];
        #pragma unroll
        for (int q = 0; q < 4; ++q) uu[q] = u4[lane + q * 64];
        const float cb = c[b];

        #pragma unroll
        for (int i = 0; i < LT; ++i) {
            const int l = l0 + i;
            const floatx4* e4 = (const floatx4*)(enc + ((size_t)l * B + b) * H);
            float acc = 0.f;
            #pragma unroll
            for (int q = 0; q < 4; ++q) {
                const floatx4 v = __builtin_nontemporal_load(e4 + lane + q * 64);
                acc += v.x * uu[q].x + v.y * uu[q].y + v.z * uu[q].z + v.w * uu[q].w;
            }
            #pragma unroll
            for (int off = 32; off > 0; off >>= 1) acc += __shfl_down(acc, off, 64);
            if (lane == 0) e_s[i][b] = acc + cb;
        }
    }
    __syncthreads();

    // softmax over b: wave i handles l0+i, lane = b
    {
        const float e = e_s[wave][lane];
        float m = e;
        #pragma unroll
        for (int off = 32; off > 0; off >>= 1) m = fmaxf(m, __shfl_xor(m, off, 64));
        const float ex = __expf(e - m);
        float s = ex;
        #pragma unroll
        for (int off = 32; off > 0; off >>= 1) s += __shfl_xor(s, off, 64);
        e_s[wave][lane] = ex / s;
    }
    __syncthreads();

    // write: thread t -> (b = t>>2, li = t&3); 16B-contiguous per b
    {
        const int b  = threadIdx.x >> 2;
        const int li = threadIdx.x & 3;
        out[(size_t)b * L + l0 + li] = e_s[li][b];
    }
}

extern "C" void kernel_launch(void* const* d_in, const int* in_sizes, int n_in,
                              void* d_out, int out_size, void* d_ws, size_t ws_size,
                              hipStream_t stream) {
    const float* hidden = (const float*)d_in[0];  // [1, 64, 1024]
    const float* enc    = (const float*)d_in[1];  // [L, 64, 1024]
    const float* W      = (const float*)d_in[2];  // [1024, 1024]
    const float* bias   = (const float*)d_in[3];  // [1024]
    float* out = (float*)d_out;                   // [64, 1, L]

    const int L = in_sizes[1] / (B * H);          // 2048

    float* part = (float*)d_ws;                   // KC*B*H floats (2 MiB)
    float* u    = part + (size_t)KC * B * H;      // B*H floats
    float* c    = u + (size_t)B * H;              // B floats

    dim3 gridA1(B / 4, KC);
    projA1<<<gridA1, 256, 0, stream>>>(hidden, W, part);

    projA2<<<B, 256, 0, stream>>>(part, hidden, bias, u, c);

    energy_softmax_fused<<<L / LT, 256, 0, stream>>>(enc, u, c, out, L);
}